// Round 1
// 418.495 us; speedup vs baseline: 1.0034x; 1.0034x over previous
//
#include <hip/hip_runtime.h>

#define N_NODES 50000
#define N_EDGES 800000
#define DIN 384
#define DH 128
#define NB 64
#define NEG 0.2f

// ---------------- bf16 helpers (exact bit ops) ----------------
__device__ __forceinline__ float bf2f(unsigned short u) {
    return __uint_as_float((unsigned)u << 16);
}
__device__ __forceinline__ unsigned short f2bf(float x) {  // RNE
    unsigned u = __float_as_uint(x);
    return (unsigned short)((u + 0x7fff + ((u >> 16) & 1)) >> 16);
}
__device__ __forceinline__ float sel4(float4 v, int k) {
    float r = v.x;
    r = (k == 1) ? v.y : r;
    r = (k == 2) ? v.z : r;
    r = (k == 3) ? v.w : r;
    return r;
}
using us8 = __attribute__((ext_vector_type(8))) unsigned short;

// ---------------- fused histogram + rank capture + edge-weight sum ----------
__global__ __launch_bounds__(256) void histew_kernel(const int* __restrict__ dst,
                                                     const float* __restrict__ ew,
                                                     int* __restrict__ cnt,
                                                     int* __restrict__ rank,
                                                     float* __restrict__ ews) {
    __shared__ float sred[4];
    const int tid = threadIdx.x;
    float v = 0.0f;
    for (int i = blockIdx.x * 256 + tid; i < N_EDGES; i += gridDim.x * 256) {
        rank[i] = atomicAdd(&cnt[dst[i]], 1);
        v += ew[i];
    }
    #pragma unroll
    for (int o = 32; o; o >>= 1) v += __shfl_down(v, o, 64);
    if ((tid & 63) == 0) sred[tid >> 6] = v;
    __syncthreads();
    if (tid == 0) atomicAdd(ews, sred[0] + sred[1] + sred[2] + sred[3]);
}

// ---------------- 3-dispatch parallel exclusive scan ----------------
__global__ void scan_a(const int* __restrict__ cnt, int* __restrict__ scanned,
                       int* __restrict__ bsums) {
    __shared__ int s[256];
    int tid = threadIdx.x;
    int i = blockIdx.x * 256 + tid;
    int v = (i < N_NODES) ? cnt[i] : 0;
    s[tid] = v; __syncthreads();
    for (int o = 1; o < 256; o <<= 1) {
        int t = (tid >= o) ? s[tid - o] : 0;
        __syncthreads();
        s[tid] += t;
        __syncthreads();
    }
    if (i < N_NODES) scanned[i] = s[tid] - v;  // exclusive
    if (tid == 255) bsums[blockIdx.x] = s[255];
}

// scan of block sums + one-time per-layer attention constants:
// consts[0..3] = cc layer0, consts[4..7] = cc layer1, consts[8] = mean(ew)
__global__ void scan_b(int* __restrict__ bsums, int nb,
                       const float* __restrict__ We0, const float* __restrict__ ae0,
                       const float* __restrict__ We1, const float* __restrict__ ae1,
                       const float* __restrict__ ews, float* __restrict__ consts) {
    __shared__ int s[256];
    int tid = threadIdx.x;
    int v = (tid < nb) ? bsums[tid] : 0;
    s[tid] = v; __syncthreads();
    for (int o = 1; o < 256; o <<= 1) {
        int t = (tid >= o) ? s[tid - o] : 0;
        __syncthreads();
        s[tid] += t;
        __syncthreads();
    }
    if (tid < nb) bsums[tid] = s[tid] - v;  // exclusive

    if (tid < 64) {
        const int l = tid;
        float p00 = We0[l] * ae0[l];
        float p01 = We0[l + 64] * ae0[l + 64];
        float p10 = We1[l] * ae1[l];
        float p11 = We1[l + 64] * ae1[l + 64];
        #pragma unroll
        for (int o = 1; o < 32; o <<= 1) {
            p00 += __shfl_xor(p00, o, 64); p01 += __shfl_xor(p01, o, 64);
            p10 += __shfl_xor(p10, o, 64); p11 += __shfl_xor(p11, o, 64);
        }
        const float c0 = __shfl(p00, 0, 64), c1 = __shfl(p00, 32, 64);
        const float c2 = __shfl(p01, 0, 64), c3 = __shfl(p01, 32, 64);
        const float d0 = __shfl(p10, 0, 64), d1 = __shfl(p10, 32, 64);
        const float d2 = __shfl(p11, 0, 64), d3 = __shfl(p11, 32, 64);
        if (l == 0) {
            consts[0] = c0; consts[1] = c1; consts[2] = c2; consts[3] = c3;
            consts[4] = d0; consts[5] = d1; consts[6] = d2; consts[7] = d3;
            consts[8] = ews[0] * (1.0f / N_EDGES);
        }
    }
}

__global__ void scan_c(const int* __restrict__ scanned, const int* __restrict__ bsums,
                       const int* __restrict__ cnt, int* __restrict__ ptr) {
    int i = blockIdx.x * 256 + threadIdx.x;
    if (i < N_NODES) {
        int p = scanned[i] + bsums[blockIdx.x];
        ptr[i] = p;
        if (i == N_NODES - 1) ptr[N_NODES] = p + cnt[i];
    }
}

// fill: atomic-free. 8 B records {src, ew_bits}; dst is implied by the CSR segment.
__global__ __launch_bounds__(256) void fill_kernel(const int* __restrict__ src,
                            const int* __restrict__ dst,
                            const float* __restrict__ ew,
                            const int* __restrict__ rank,
                            const int* __restrict__ ptr,
                            int2* __restrict__ recE) {
    const int e0 = (blockIdx.x * 256 + threadIdx.x) * 4;
    if (e0 >= N_EDGES) return;
    const int4 d4 = *(const int4*)(dst + e0);
    const int4 s4 = *(const int4*)(src + e0);
    const int4 r4 = *(const int4*)(rank + e0);
    const float4 w4 = *(const float4*)(ew + e0);
    recE[ptr[d4.x] + r4.x] = make_int2(s4.x, __float_as_int(w4.x));
    recE[ptr[d4.y] + r4.y] = make_int2(s4.y, __float_as_int(w4.y));
    recE[ptr[d4.z] + r4.z] = make_int2(s4.z, __float_as_int(w4.z));
    recE[ptr[d4.w] + r4.w] = make_int2(s4.w, __float_as_int(w4.w));
}

// ---------------- MFMA bf16 GEMM: C[M,128] = A[M,K] @ W[K,128] (+bias) ----------
template<int K, bool BF16OUT>
__global__ __launch_bounds__(256) void mfma_gemm(const float* __restrict__ A,
                                                 const float* __restrict__ W,
                                                 const float* __restrict__ bias,
                                                 void* __restrict__ Cv, int M,
                                                 const float* __restrict__ a_s,
                                                 const float* __restrict__ a_d,
                                                 float* __restrict__ asrc_o,
                                                 float* __restrict__ adst_o)
{
    constexpr int BM = 64, BK = 32;
    constexpr int LS = 40;   // LDS row stride in bf16 (80 B: conflict-spreading pad)
    __shared__ unsigned short As[BM * LS];   // [m][k]
    __shared__ unsigned short Bs[DH * LS];   // [n][k]  (W transposed)
    using short8 = __attribute__((ext_vector_type(8))) short;
    using f32x4  = __attribute__((ext_vector_type(4))) float;

    const int tid = threadIdx.x;
    const int w = tid >> 6, l = tid & 63;
    const int lane16 = l & 15, quad = l >> 4;
    const int m0 = blockIdx.x * BM;

    f32x4 acc[8] = {};

    const int ar = tid >> 2, af = tid & 3;
    int arow = m0 + ar; if (arow >= M) arow = M - 1;
    const float* Ap = A + (size_t)arow * K;
    const int bn = tid & 127, bq = tid >> 7;

    for (int k0 = 0; k0 < K; k0 += BK) {
        __syncthreads();
        #pragma unroll
        for (int i = 0; i < 2; ++i) {
            const int f4 = af + 4 * i;
            float4 v = *(const float4*)(Ap + k0 + f4 * 4);
            ushort4 u = {f2bf(v.x), f2bf(v.y), f2bf(v.z), f2bf(v.w)};
            *(ushort4*)&As[ar * LS + f4 * 4] = u;
        }
        #pragma unroll
        for (int i = 0; i < 4; ++i) {
            const int kq = bq + 2 * i;   // 0..7
            float v0 = W[(size_t)(k0 + kq * 4 + 0) * DH + bn];
            float v1 = W[(size_t)(k0 + kq * 4 + 1) * DH + bn];
            float v2 = W[(size_t)(k0 + kq * 4 + 2) * DH + bn];
            float v3 = W[(size_t)(k0 + kq * 4 + 3) * DH + bn];
            ushort4 u = {f2bf(v0), f2bf(v1), f2bf(v2), f2bf(v3)};
            *(ushort4*)&Bs[bn * LS + kq * 4] = u;
        }
        __syncthreads();
        short8 afrag = *(short8*)&As[(w * 16 + lane16) * LS + quad * 8];
        #pragma unroll
        for (int nt = 0; nt < 8; ++nt) {
            short8 bfrag = *(short8*)&Bs[(nt * 16 + lane16) * LS + quad * 8];
            acc[nt] = __builtin_amdgcn_mfma_f32_16x16x32_bf16(afrag, bfrag, acc[nt], 0, 0, 0);
        }
    }

    const int orow0 = m0 + w * 16 + quad * 4;
    #pragma unroll
    for (int nt = 0; nt < 8; ++nt) {
        const int col = nt * 16 + lane16;
        const float bv = BF16OUT ? 0.0f : bias[col];
        #pragma unroll
        for (int r = 0; r < 4; ++r) {
            const int row = orow0 + r;
            if (row < M) {
                if constexpr (BF16OUT)
                    ((unsigned short*)Cv)[(size_t)row * DH + col] = f2bf(acc[nt][r]);
                else
                    ((float*)Cv)[(size_t)row * DH + col] = acc[nt][r] + bv;
            }
        }
    }

    if constexpr (BF16OUT) {
        float psh[4][4] = {}, pdh[4][4] = {};   // [head][r]
        #pragma unroll
        for (int nt = 0; nt < 8; ++nt) {
            const int hd = nt >> 1;
            const float asv = a_s[nt * 16 + lane16];
            const float adv = a_d[nt * 16 + lane16];
            #pragma unroll
            for (int r = 0; r < 4; ++r) {
                psh[hd][r] = fmaf(acc[nt][r], asv, psh[hd][r]);
                pdh[hd][r] = fmaf(acc[nt][r], adv, pdh[hd][r]);
            }
        }
        #pragma unroll
        for (int o = 1; o < 16; o <<= 1) {
            #pragma unroll
            for (int hd = 0; hd < 4; ++hd)
                #pragma unroll
                for (int r = 0; r < 4; ++r) {
                    psh[hd][r] += __shfl_xor(psh[hd][r], o, 64);
                    pdh[hd][r] += __shfl_xor(pdh[hd][r], o, 64);
                }
        }
        if (lane16 == 0) {
            #pragma unroll
            for (int r = 0; r < 4; ++r) {
                const int row = orow0 + r;
                if (row < M) {
                    float4 o1 = {psh[0][r], psh[1][r], psh[2][r], psh[3][r]};
                    float4 o2 = {pdh[0][r], pdh[1][r], pdh[2][r], pdh[3][r]};
                    *(float4*)(asrc_o + (size_t)row * 4) = o1;
                    *(float4*)(adst_o + (size_t)row * 4) = o2;
                }
            }
        }
    }
}

// ---------------- msg: fused alpha + gather + softmax-norm + LN + ELU + res ----
// persistent grid-stride; 4 nodes / 256-thr block per iteration.
#define MSG_NPB 4
#define MSG_GRID 2048
__global__ __launch_bounds__(256) void msg_kernel(
    const unsigned short* __restrict__ h, const float* __restrict__ asrc,
    const float* __restrict__ adst, const float* __restrict__ xres,
    const int* __restrict__ indptr, const int2* __restrict__ recE,
    const float* __restrict__ consts, const int layer,
    const float* __restrict__ bias, const float* __restrict__ gamma,
    const float* __restrict__ beta, float* __restrict__ xout)
{
    const int l = threadIdx.x & 63;
    const int wv = threadIdx.x >> 6;
    const int sub2 = l >> 4, c8 = l & 15, hd8 = c8 >> 2;

    const float4 ccv = *(const float4*)(consts + layer * 4);
    const float cc_l = sel4(ccv, hd8);
    const float ewm = consts[8];
    const unsigned short* hb = h + c8 * 8;

    for (int n = blockIdx.x * MSG_NPB + wv; n < N_NODES; n += MSG_GRID * MSG_NPB) {
        const int st = indptr[n];
        const int deg = indptr[n + 1] - st;
        const float4 ad4 = *(const float4*)(adst + (size_t)n * 4);
        const float4 as4 = *(const float4*)(asrc + (size_t)n * 4);
        const float ad_l = sel4(ad4, hd8);
        const float as_l = sel4(as4, hd8);
        // self-loop coefficient
        float a0 = as_l + ad_l + ewm * cc_l;
        a0 = a0 > 0.f ? a0 : NEG * a0;
        const float pv0_l = __expf(a0);   // |alpha| << 1 -> exact softmax w/o max-shift

        float dsum = 0.f;
        float acc8[8] = {};
        if (sub2 == 0) {
            us8 u = *(const us8*)(hb + (size_t)n * DH);
            #pragma unroll
            for (int i = 0; i < 8; ++i) acc8[i] = pv0_l * bf2f(u[i]);
        }

        const int2* rq = recE + st;
        int e = sub2;
        for (; e + 12 < deg; e += 16) {
            const int2 r0 = rq[e],     r1 = rq[e + 4];
            const int2 r2 = rq[e + 8], r3 = rq[e + 12];
            const float av0 = asrc[(size_t)r0.x * 4 + hd8];
            const float av1 = asrc[(size_t)r1.x * 4 + hd8];
            const float av2 = asrc[(size_t)r2.x * 4 + hd8];
            const float av3 = asrc[(size_t)r3.x * 4 + hd8];
            us8 u0 = *(const us8*)(hb + (size_t)r0.x * DH);
            us8 u1 = *(const us8*)(hb + (size_t)r1.x * DH);
            us8 u2 = *(const us8*)(hb + (size_t)r2.x * DH);
            us8 u3 = *(const us8*)(hb + (size_t)r3.x * DH);
            float al0 = av0 + ad_l + __int_as_float(r0.y) * cc_l;
            float al1 = av1 + ad_l + __int_as_float(r1.y) * cc_l;
            float al2 = av2 + ad_l + __int_as_float(r2.y) * cc_l;
            float al3 = av3 + ad_l + __int_as_float(r3.y) * cc_l;
            al0 = al0 > 0.f ? al0 : NEG * al0;
            al1 = al1 > 0.f ? al1 : NEG * al1;
            al2 = al2 > 0.f ? al2 : NEG * al2;
            al3 = al3 > 0.f ? al3 : NEG * al3;
            const float c0 = __expf(al0), c1 = __expf(al1);
            const float c2 = __expf(al2), c3 = __expf(al3);
            dsum += (c0 + c1) + (c2 + c3);
            #pragma unroll
            for (int i = 0; i < 8; ++i)
                acc8[i] = fmaf(c0, bf2f(u0[i]),
                          fmaf(c1, bf2f(u1[i]),
                          fmaf(c2, bf2f(u2[i]),
                          fmaf(c3, bf2f(u3[i]), acc8[i]))));
        }
        for (; e < deg; e += 4) {
            const int2 r = rq[e];
            const float av = asrc[(size_t)r.x * 4 + hd8];
            us8 u = *(const us8*)(hb + (size_t)r.x * DH);
            float al = av + ad_l + __int_as_float(r.y) * cc_l;
            al = al > 0.f ? al : NEG * al;
            const float c = __expf(al);
            dsum += c;
            #pragma unroll
            for (int i = 0; i < 8; ++i) acc8[i] = fmaf(c, bf2f(u[i]), acc8[i]);
        }

        // reduce over the 4 edge-parity groups (bits 4,5 of lane id)
        #pragma unroll
        for (int i = 0; i < 8; ++i) {
            acc8[i] += __shfl_xor(acc8[i], 16, 64);
            acc8[i] += __shfl_xor(acc8[i], 32, 64);
        }
        dsum += __shfl_xor(dsum, 16, 64);
        dsum += __shfl_xor(dsum, 32, 64);

        const float inv_d = 1.0f / (dsum + pv0_l + 1e-16f);
        const float4 b4a = *(const float4*)(bias + c8 * 8);
        const float4 b4b = *(const float4*)(bias + c8 * 8 + 4);
        float y[8];
        y[0] = acc8[0] * inv_d + b4a.x; y[1] = acc8[1] * inv_d + b4a.y;
        y[2] = acc8[2] * inv_d + b4a.z; y[3] = acc8[3] * inv_d + b4a.w;
        y[4] = acc8[4] * inv_d + b4b.x; y[5] = acc8[5] * inv_d + b4b.y;
        y[6] = acc8[6] * inv_d + b4b.z; y[7] = acc8[7] * inv_d + b4b.w;

        float s1 = 0.f, s2 = 0.f;
        #pragma unroll
        for (int i = 0; i < 8; ++i) { s1 += y[i]; s2 += y[i] * y[i]; }
        #pragma unroll
        for (int o = 1; o < 16; o <<= 1) {
            s1 += __shfl_xor(s1, o, 64);
            s2 += __shfl_xor(s2, o, 64);
        }
        const float mu = s1 * (1.0f / DH);
        const float var = s2 * (1.0f / DH) - mu * mu;
        const float rs = rsqrtf(var + 1e-5f);

        if (sub2 == 0) {
            const float4 g4a = *(const float4*)(gamma + c8 * 8);
            const float4 g4b = *(const float4*)(gamma + c8 * 8 + 4);
            const float4 e4a = *(const float4*)(beta + c8 * 8);
            const float4 e4b = *(const float4*)(beta + c8 * 8 + 4);
            const float4 r4a = *(const float4*)(xres + (size_t)n * DH + c8 * 8);
            const float4 r4b = *(const float4*)(xres + (size_t)n * DH + c8 * 8 + 4);
            const float gv[8] = {g4a.x, g4a.y, g4a.z, g4a.w, g4b.x, g4b.y, g4b.z, g4b.w};
            const float ev[8] = {e4a.x, e4a.y, e4a.z, e4a.w, e4b.x, e4b.y, e4b.z, e4b.w};
            const float rv[8] = {r4a.x, r4a.y, r4a.z, r4a.w, r4b.x, r4b.y, r4b.z, r4b.w};
            float z[8];
            #pragma unroll
            for (int i = 0; i < 8; ++i) {
                float t = (y[i] - mu) * rs * gv[i] + ev[i];
                z[i] = (t > 0.f ? t : __expf(t) - 1.0f) + rv[i];
            }
            *(float4*)(xout + (size_t)n * DH + c8 * 8)     = *(float4*)&z[0];
            *(float4*)(xout + (size_t)n * DH + c8 * 8 + 4) = *(float4*)&z[4];
        }
    }
}

// ---------------- global mean pool ----------------
#define PNODES 64
__global__ __launch_bounds__(128) void pool_kernel(const float* __restrict__ x,
        const int* __restrict__ batch, float* __restrict__ pool, int* __restrict__ gcnt)
{
    int t = threadIdx.x;
    int n0 = blockIdx.x * PNODES;
    if (n0 >= N_NODES) return;
    int n1 = min(n0 + PNODES, N_NODES);
    float acc = 0.f; int cn = 0;
    int curb = batch[n0];
    for (int n = n0; n < n1; ++n) {
        int b = batch[n];
        if (b != curb) {
            atomicAdd(&pool[(size_t)curb * DH + t], acc);
            if (t == 0) atomicAdd(&gcnt[curb], cn);
            acc = 0.f; cn = 0; curb = b;
        }
        acc += x[(size_t)n * DH + t];
        ++cn;
    }
    atomicAdd(&pool[(size_t)curb * DH + t], acc);
    if (t == 0) atomicAdd(&gcnt[curb], cn);
}

__global__ void div_kernel(const float* __restrict__ pool, const int* __restrict__ gcnt,
                           float* __restrict__ out)
{
    int i = blockIdx.x * blockDim.x + threadIdx.x;
    if (i < NB * DH) {
        float c = (float)gcnt[i >> 7];
        out[i] = pool[i] / fmaxf(c, 1.0f);
    }
}

// ---------------- launch ----------------
extern "C" void kernel_launch(void* const* d_in, const int* in_sizes, int n_in,
                              void* d_out, int out_size, void* d_ws, size_t ws_size,
                              hipStream_t stream)
{
    const float* nf    = (const float*)d_in[0];
    const int*   esrc  = (const int*)d_in[1];
    const int*   edst  = esrc + N_EDGES;
    const float* ew    = (const float*)d_in[2];
    const int*   batch = (const int*)d_in[3];
    const float* Wp    = (const float*)d_in[4];
    const float* bp    = (const float*)d_in[5];
    const float* Wl[2]  = {(const float*)d_in[6],  (const float*)d_in[14]};
    const float* asl[2] = {(const float*)d_in[7],  (const float*)d_in[15]};
    const float* adl[2] = {(const float*)d_in[8],  (const float*)d_in[16]};
    const float* Wel[2] = {(const float*)d_in[9],  (const float*)d_in[17]};
    const float* ael[2] = {(const float*)d_in[10], (const float*)d_in[18]};
    const float* bl[2]  = {(const float*)d_in[11], (const float*)d_in[19]};
    const float* gl[2]  = {(const float*)d_in[12], (const float*)d_in[20]};
    const float* bel[2] = {(const float*)d_in[13], (const float*)d_in[21]};
    float* outp = (float*)d_out;

    char* w = (char*)d_ws;
    auto alloc = [&](size_t bytes) { char* p = w; w += (bytes + 255) & ~255ull; return p; };
    float* xA     = (float*)alloc((size_t)N_NODES * DH * 4);
    float* xB     = (float*)alloc((size_t)N_NODES * DH * 4);
    unsigned short* hbuf = (unsigned short*)alloc((size_t)N_NODES * DH * 2);
    float* asrc   = (float*)alloc((size_t)N_NODES * 4 * 4);
    float* adst   = (float*)alloc((size_t)N_NODES * 4 * 4);
    // contiguous zero-init group: pool | gcnt | ews | cnt  (one memset)
    float* pool   = (float*)alloc((size_t)NB * DH * 4);     // 32768 B
    int* gcnt     = (int*)alloc(256);
    float* ews    = (float*)alloc(256);
    int* cnt      = (int*)alloc((size_t)N_NODES * 4);
    int* scanned  = (int*)alloc((size_t)N_NODES * 4);
    int* bsums    = (int*)alloc(1024);
    int* ptr      = (int*)alloc((size_t)(N_NODES + 8) * 4);
    int* rank     = (int*)alloc((size_t)N_EDGES * 4);
    int2* recE    = (int2*)alloc((size_t)N_EDGES * 8);
    float* consts = (float*)alloc(256);

    hipMemsetAsync(pool, 0, (size_t)NB * DH * 4 + 256 + 256 + (size_t)N_NODES * 4, stream);

    const int sb = (N_NODES + 255) / 256;  // 196

    histew_kernel<<<1024, 256, 0, stream>>>(edst, ew, cnt, rank, ews);
    scan_a<<<sb, 256, 0, stream>>>(cnt, scanned, bsums);
    scan_b<<<1, 256, 0, stream>>>(bsums, sb, Wel[0], ael[0], Wel[1], ael[1], ews, consts);
    scan_c<<<sb, 256, 0, stream>>>(scanned, bsums, cnt, ptr);
    fill_kernel<<<(N_EDGES / 4 + 255) / 256, 256, 0, stream>>>(esrc, edst, ew, rank, ptr, recE);

    const int gb = (N_NODES + 63) / 64;  // 782
    mfma_gemm<DIN, false><<<gb, 256, 0, stream>>>(nf, Wp, bp, xA, N_NODES,
                                                  nullptr, nullptr, nullptr, nullptr);

    const float* xin = xA;
    float* xout = xB;
    for (int l = 0; l < 2; ++l) {
        mfma_gemm<DH, true><<<gb, 256, 0, stream>>>(xin, Wl[l], nullptr, hbuf, N_NODES,
                                                    asl[l], adl[l], asrc, adst);
        msg_kernel<<<MSG_GRID, 256, 0, stream>>>(
            hbuf, asrc, adst, xin, ptr, recE, consts, l,
            bl[l], gl[l], bel[l], xout);
        float* tmp = (float*)xin; xin = xout; xout = tmp;
    }

    pool_kernel<<<(N_NODES + PNODES - 1) / PNODES, 128, 0, stream>>>(xin, batch, pool, gcnt);
    div_kernel<<<(NB * DH + 255) / 256, 256, 0, stream>>>(pool, gcnt, outp);
}

// Round 2
// 378.429 us; speedup vs baseline: 1.1096x; 1.1059x over previous
//
#include <hip/hip_runtime.h>

#define N_NODES 50000
#define N_EDGES 800000
#define DIN 384
#define DH 128
#define NB 64
#define NEG 0.2f

// ---------------- bf16 helpers (exact bit ops) ----------------
__device__ __forceinline__ float bf2f(unsigned short u) {
    return __uint_as_float((unsigned)u << 16);
}
__device__ __forceinline__ unsigned short f2bf(float x) {  // RNE
    unsigned u = __float_as_uint(x);
    return (unsigned short)((u + 0x7fff + ((u >> 16) & 1)) >> 16);
}
__device__ __forceinline__ float sel4(float4 v, int k) {
    float r = v.x;
    r = (k == 1) ? v.y : r;
    r = (k == 2) ? v.z : r;
    r = (k == 3) ? v.w : r;
    return r;
}
using us8 = __attribute__((ext_vector_type(8))) unsigned short;

// ---------------- fused histogram + rank capture + edge-weight sum ----------
__global__ __launch_bounds__(256) void histew_kernel(const int* __restrict__ dst,
                                                     const float* __restrict__ ew,
                                                     int* __restrict__ cnt,
                                                     int* __restrict__ rank,
                                                     float* __restrict__ ews) {
    __shared__ float sred[4];
    const int tid = threadIdx.x;
    float v = 0.0f;
    for (int i = blockIdx.x * 256 + tid; i < N_EDGES; i += gridDim.x * 256) {
        rank[i] = atomicAdd(&cnt[dst[i]], 1);
        v += ew[i];
    }
    #pragma unroll
    for (int o = 32; o; o >>= 1) v += __shfl_down(v, o, 64);
    if ((tid & 63) == 0) sred[tid >> 6] = v;
    __syncthreads();
    if (tid == 0) atomicAdd(ews, sred[0] + sred[1] + sred[2] + sred[3]);
}

// ---------------- 3-dispatch parallel exclusive scan ----------------
__global__ void scan_a(const int* __restrict__ cnt, int* __restrict__ scanned,
                       int* __restrict__ bsums) {
    __shared__ int s[256];
    int tid = threadIdx.x;
    int i = blockIdx.x * 256 + tid;
    int v = (i < N_NODES) ? cnt[i] : 0;
    s[tid] = v; __syncthreads();
    for (int o = 1; o < 256; o <<= 1) {
        int t = (tid >= o) ? s[tid - o] : 0;
        __syncthreads();
        s[tid] += t;
        __syncthreads();
    }
    if (i < N_NODES) scanned[i] = s[tid] - v;  // exclusive
    if (tid == 255) bsums[blockIdx.x] = s[255];
}

// scan of block sums + one-time per-layer attention constants:
// consts[0..3] = cc layer0, consts[4..7] = cc layer1, consts[8] = mean(ew)
__global__ void scan_b(int* __restrict__ bsums, int nb,
                       const float* __restrict__ We0, const float* __restrict__ ae0,
                       const float* __restrict__ We1, const float* __restrict__ ae1,
                       const float* __restrict__ ews, float* __restrict__ consts) {
    __shared__ int s[256];
    int tid = threadIdx.x;
    int v = (tid < nb) ? bsums[tid] : 0;
    s[tid] = v; __syncthreads();
    for (int o = 1; o < 256; o <<= 1) {
        int t = (tid >= o) ? s[tid - o] : 0;
        __syncthreads();
        s[tid] += t;
        __syncthreads();
    }
    if (tid < nb) bsums[tid] = s[tid] - v;  // exclusive

    if (tid < 64) {
        const int l = tid;
        float p00 = We0[l] * ae0[l];
        float p01 = We0[l + 64] * ae0[l + 64];
        float p10 = We1[l] * ae1[l];
        float p11 = We1[l + 64] * ae1[l + 64];
        #pragma unroll
        for (int o = 1; o < 32; o <<= 1) {
            p00 += __shfl_xor(p00, o, 64); p01 += __shfl_xor(p01, o, 64);
            p10 += __shfl_xor(p10, o, 64); p11 += __shfl_xor(p11, o, 64);
        }
        const float c0 = __shfl(p00, 0, 64), c1 = __shfl(p00, 32, 64);
        const float c2 = __shfl(p01, 0, 64), c3 = __shfl(p01, 32, 64);
        const float d0 = __shfl(p10, 0, 64), d1 = __shfl(p10, 32, 64);
        const float d2 = __shfl(p11, 0, 64), d3 = __shfl(p11, 32, 64);
        if (l == 0) {
            consts[0] = c0; consts[1] = c1; consts[2] = c2; consts[3] = c3;
            consts[4] = d0; consts[5] = d1; consts[6] = d2; consts[7] = d3;
            consts[8] = ews[0] * (1.0f / N_EDGES);
        }
    }
}

__global__ void scan_c(const int* __restrict__ scanned, const int* __restrict__ bsums,
                       const int* __restrict__ cnt, int* __restrict__ ptr) {
    int i = blockIdx.x * 256 + threadIdx.x;
    if (i < N_NODES) {
        int p = scanned[i] + bsums[blockIdx.x];
        ptr[i] = p;
        if (i == N_NODES - 1) ptr[N_NODES] = p + cnt[i];
    }
}

// fill: atomic-free. 8 B records {src, ew_bits}; dst is implied by the CSR segment.
__global__ __launch_bounds__(256) void fill_kernel(const int* __restrict__ src,
                            const int* __restrict__ dst,
                            const float* __restrict__ ew,
                            const int* __restrict__ rank,
                            const int* __restrict__ ptr,
                            int2* __restrict__ recE) {
    const int e0 = (blockIdx.x * 256 + threadIdx.x) * 4;
    if (e0 >= N_EDGES) return;
    const int4 d4 = *(const int4*)(dst + e0);
    const int4 s4 = *(const int4*)(src + e0);
    const int4 r4 = *(const int4*)(rank + e0);
    const float4 w4 = *(const float4*)(ew + e0);
    recE[ptr[d4.x] + r4.x] = make_int2(s4.x, __float_as_int(w4.x));
    recE[ptr[d4.y] + r4.y] = make_int2(s4.y, __float_as_int(w4.y));
    recE[ptr[d4.z] + r4.z] = make_int2(s4.z, __float_as_int(w4.z));
    recE[ptr[d4.w] + r4.w] = make_int2(s4.w, __float_as_int(w4.w));
}

// ---------------- MFMA bf16 GEMM: C[M,128] = A[M,K] @ W[K,128] (+bias) ----------
template<int K, bool BF16OUT>
__global__ __launch_bounds__(256) void mfma_gemm(const float* __restrict__ A,
                                                 const float* __restrict__ W,
                                                 const float* __restrict__ bias,
                                                 void* __restrict__ Cv, int M,
                                                 const float* __restrict__ a_s,
                                                 const float* __restrict__ a_d,
                                                 float* __restrict__ asrc_o,
                                                 float* __restrict__ adst_o)
{
    constexpr int BM = 64, BK = 32;
    constexpr int LS = 40;   // LDS row stride in bf16 (80 B: conflict-spreading pad)
    __shared__ unsigned short As[BM * LS];   // [m][k]
    __shared__ unsigned short Bs[DH * LS];   // [n][k]  (W transposed)
    using short8 = __attribute__((ext_vector_type(8))) short;
    using f32x4  = __attribute__((ext_vector_type(4))) float;

    const int tid = threadIdx.x;
    const int w = tid >> 6, l = tid & 63;
    const int lane16 = l & 15, quad = l >> 4;
    const int m0 = blockIdx.x * BM;

    f32x4 acc[8] = {};

    const int ar = tid >> 2, af = tid & 3;
    int arow = m0 + ar; if (arow >= M) arow = M - 1;
    const float* Ap = A + (size_t)arow * K;
    const int bn = tid & 127, bq = tid >> 7;

    for (int k0 = 0; k0 < K; k0 += BK) {
        __syncthreads();
        #pragma unroll
        for (int i = 0; i < 2; ++i) {
            const int f4 = af + 4 * i;
            float4 v = *(const float4*)(Ap + k0 + f4 * 4);
            ushort4 u = {f2bf(v.x), f2bf(v.y), f2bf(v.z), f2bf(v.w)};
            *(ushort4*)&As[ar * LS + f4 * 4] = u;
        }
        #pragma unroll
        for (int i = 0; i < 4; ++i) {
            const int kq = bq + 2 * i;   // 0..7
            float v0 = W[(size_t)(k0 + kq * 4 + 0) * DH + bn];
            float v1 = W[(size_t)(k0 + kq * 4 + 1) * DH + bn];
            float v2 = W[(size_t)(k0 + kq * 4 + 2) * DH + bn];
            float v3 = W[(size_t)(k0 + kq * 4 + 3) * DH + bn];
            ushort4 u = {f2bf(v0), f2bf(v1), f2bf(v2), f2bf(v3)};
            *(ushort4*)&Bs[bn * LS + kq * 4] = u;
        }
        __syncthreads();
        short8 afrag = *(short8*)&As[(w * 16 + lane16) * LS + quad * 8];
        #pragma unroll
        for (int nt = 0; nt < 8; ++nt) {
            short8 bfrag = *(short8*)&Bs[(nt * 16 + lane16) * LS + quad * 8];
            acc[nt] = __builtin_amdgcn_mfma_f32_16x16x32_bf16(afrag, bfrag, acc[nt], 0, 0, 0);
        }
    }

    const int orow0 = m0 + w * 16 + quad * 4;
    #pragma unroll
    for (int nt = 0; nt < 8; ++nt) {
        const int col = nt * 16 + lane16;
        const float bv = BF16OUT ? 0.0f : bias[col];
        #pragma unroll
        for (int r = 0; r < 4; ++r) {
            const int row = orow0 + r;
            if (row < M) {
                if constexpr (BF16OUT)
                    ((unsigned short*)Cv)[(size_t)row * DH + col] = f2bf(acc[nt][r]);
                else
                    ((float*)Cv)[(size_t)row * DH + col] = acc[nt][r] + bv;
            }
        }
    }

    if constexpr (BF16OUT) {
        float psh[4][4] = {}, pdh[4][4] = {};   // [head][r]
        #pragma unroll
        for (int nt = 0; nt < 8; ++nt) {
            const int hd = nt >> 1;
            const float asv = a_s[nt * 16 + lane16];
            const float adv = a_d[nt * 16 + lane16];
            #pragma unroll
            for (int r = 0; r < 4; ++r) {
                psh[hd][r] = fmaf(acc[nt][r], asv, psh[hd][r]);
                pdh[hd][r] = fmaf(acc[nt][r], adv, pdh[hd][r]);
            }
        }
        #pragma unroll
        for (int o = 1; o < 16; o <<= 1) {
            #pragma unroll
            for (int hd = 0; hd < 4; ++hd)
                #pragma unroll
                for (int r = 0; r < 4; ++r) {
                    psh[hd][r] += __shfl_xor(psh[hd][r], o, 64);
                    pdh[hd][r] += __shfl_xor(pdh[hd][r], o, 64);
                }
        }
        if (lane16 == 0) {
            #pragma unroll
            for (int r = 0; r < 4; ++r) {
                const int row = orow0 + r;
                if (row < M) {
                    float4 o1 = {psh[0][r], psh[1][r], psh[2][r], psh[3][r]};
                    float4 o2 = {pdh[0][r], pdh[1][r], pdh[2][r], pdh[3][r]};
                    *(float4*)(asrc_o + (size_t)row * 4) = o1;
                    *(float4*)(adst_o + (size_t)row * 4) = o2;
                }
            }
        }
    }
}

// ---------------- msg: fused alpha + gather + softmax-norm + LN + ELU + res ----
// One node per 16-lane group (4 nodes/wave, 16 nodes/block). Each lane owns 8
// channels (c8*8..c8*8+7). No cross-parity reduces; only LN's 16-lane reduce.
#define MSG_NPB 16
__global__ __launch_bounds__(256) void msg_kernel(
    const unsigned short* __restrict__ h, const float* __restrict__ asrc,
    const float* __restrict__ adst, const float* __restrict__ xres,
    const int* __restrict__ indptr, const int2* __restrict__ recE,
    const float* __restrict__ consts, const int layer,
    const float* __restrict__ bias, const float* __restrict__ gamma,
    const float* __restrict__ beta, float* __restrict__ xout)
{
    const int l = threadIdx.x & 63;
    const int wv = threadIdx.x >> 6;
    const int grp = l >> 4;          // node slot within wave (0..3)
    const int c8 = l & 15;           // channel lane: channels [c8*8, c8*8+8)
    const int hd8 = c8 >> 2;         // head of those channels

    const int n = blockIdx.x * MSG_NPB + wv * 4 + grp;   // grid is exact: 3125*16=50000

    const float4 ccv = *(const float4*)(consts + layer * 4);
    const float cc_l = sel4(ccv, hd8);
    const float ewm = consts[8];
    const unsigned short* hb = h + c8 * 8;

    const int st = indptr[n];
    const int deg = indptr[n + 1] - st;
    const float ad_l = adst[(size_t)n * 4 + hd8];
    const float as_l = asrc[(size_t)n * 4 + hd8];

    // self-loop coefficient (|alpha| << 1 -> exp without max-shift is exact softmax)
    float a0 = as_l + ad_l + ewm * cc_l;
    a0 = a0 > 0.f ? a0 : NEG * a0;
    const float pv0_l = __expf(a0);

    float dsum = 0.f;
    float acc8[8];
    {
        us8 u = *(const us8*)(hb + (size_t)n * DH);
        #pragma unroll
        for (int i = 0; i < 8; ++i) acc8[i] = pv0_l * bf2f(u[i]);
    }

    const int2* rq = recE + st;
    int e = 0;
    for (; e + 3 < deg; e += 4) {
        const int2 r0 = rq[e],     r1 = rq[e + 1];
        const int2 r2 = rq[e + 2], r3 = rq[e + 3];
        const float av0 = asrc[(size_t)r0.x * 4 + hd8];
        const float av1 = asrc[(size_t)r1.x * 4 + hd8];
        const float av2 = asrc[(size_t)r2.x * 4 + hd8];
        const float av3 = asrc[(size_t)r3.x * 4 + hd8];
        us8 u0 = *(const us8*)(hb + (size_t)r0.x * DH);
        us8 u1 = *(const us8*)(hb + (size_t)r1.x * DH);
        us8 u2 = *(const us8*)(hb + (size_t)r2.x * DH);
        us8 u3 = *(const us8*)(hb + (size_t)r3.x * DH);
        float al0 = av0 + ad_l + __int_as_float(r0.y) * cc_l;
        float al1 = av1 + ad_l + __int_as_float(r1.y) * cc_l;
        float al2 = av2 + ad_l + __int_as_float(r2.y) * cc_l;
        float al3 = av3 + ad_l + __int_as_float(r3.y) * cc_l;
        al0 = al0 > 0.f ? al0 : NEG * al0;
        al1 = al1 > 0.f ? al1 : NEG * al1;
        al2 = al2 > 0.f ? al2 : NEG * al2;
        al3 = al3 > 0.f ? al3 : NEG * al3;
        const float c0 = __expf(al0), c1 = __expf(al1);
        const float c2 = __expf(al2), c3 = __expf(al3);
        dsum += (c0 + c1) + (c2 + c3);
        #pragma unroll
        for (int i = 0; i < 8; ++i)
            acc8[i] = fmaf(c0, bf2f(u0[i]),
                      fmaf(c1, bf2f(u1[i]),
                      fmaf(c2, bf2f(u2[i]),
                      fmaf(c3, bf2f(u3[i]), acc8[i]))));
    }
    for (; e < deg; ++e) {
        const int2 r = rq[e];
        const float av = asrc[(size_t)r.x * 4 + hd8];
        us8 u = *(const us8*)(hb + (size_t)r.x * DH);
        float al = av + ad_l + __int_as_float(r.y) * cc_l;
        al = al > 0.f ? al : NEG * al;
        const float c = __expf(al);
        dsum += c;
        #pragma unroll
        for (int i = 0; i < 8; ++i) acc8[i] = fmaf(c, bf2f(u[i]), acc8[i]);
    }

    const float inv_d = 1.0f / (dsum + pv0_l + 1e-16f);
    const float4 b4a = *(const float4*)(bias + c8 * 8);
    const float4 b4b = *(const float4*)(bias + c8 * 8 + 4);
    float y[8];
    y[0] = acc8[0] * inv_d + b4a.x; y[1] = acc8[1] * inv_d + b4a.y;
    y[2] = acc8[2] * inv_d + b4a.z; y[3] = acc8[3] * inv_d + b4a.w;
    y[4] = acc8[4] * inv_d + b4b.x; y[5] = acc8[5] * inv_d + b4b.y;
    y[6] = acc8[6] * inv_d + b4b.z; y[7] = acc8[7] * inv_d + b4b.w;

    float s1 = 0.f, s2 = 0.f;
    #pragma unroll
    for (int i = 0; i < 8; ++i) { s1 += y[i]; s2 += y[i] * y[i]; }
    #pragma unroll
    for (int o = 1; o < 16; o <<= 1) {   // stays within the 16-lane group
        s1 += __shfl_xor(s1, o, 64);
        s2 += __shfl_xor(s2, o, 64);
    }
    const float mu = s1 * (1.0f / DH);
    const float var = s2 * (1.0f / DH) - mu * mu;
    const float rs = rsqrtf(var + 1e-5f);

    const float4 g4a = *(const float4*)(gamma + c8 * 8);
    const float4 g4b = *(const float4*)(gamma + c8 * 8 + 4);
    const float4 e4a = *(const float4*)(beta + c8 * 8);
    const float4 e4b = *(const float4*)(beta + c8 * 8 + 4);
    const float4 r4a = *(const float4*)(xres + (size_t)n * DH + c8 * 8);
    const float4 r4b = *(const float4*)(xres + (size_t)n * DH + c8 * 8 + 4);
    const float gv[8] = {g4a.x, g4a.y, g4a.z, g4a.w, g4b.x, g4b.y, g4b.z, g4b.w};
    const float ev[8] = {e4a.x, e4a.y, e4a.z, e4a.w, e4b.x, e4b.y, e4b.z, e4b.w};
    const float rv[8] = {r4a.x, r4a.y, r4a.z, r4a.w, r4b.x, r4b.y, r4b.z, r4b.w};
    float z[8];
    #pragma unroll
    for (int i = 0; i < 8; ++i) {
        float t = (y[i] - mu) * rs * gv[i] + ev[i];
        z[i] = (t > 0.f ? t : __expf(t) - 1.0f) + rv[i];
    }
    *(float4*)(xout + (size_t)n * DH + c8 * 8)     = *(float4*)&z[0];
    *(float4*)(xout + (size_t)n * DH + c8 * 8 + 4) = *(float4*)&z[4];
}

// ---------------- global mean pool ----------------
#define PNODES 64
__global__ __launch_bounds__(128) void pool_kernel(const float* __restrict__ x,
        const int* __restrict__ batch, float* __restrict__ pool, int* __restrict__ gcnt)
{
    int t = threadIdx.x;
    int n0 = blockIdx.x * PNODES;
    if (n0 >= N_NODES) return;
    int n1 = min(n0 + PNODES, N_NODES);
    float acc = 0.f; int cn = 0;
    int curb = batch[n0];
    for (int n = n0; n < n1; ++n) {
        int b = batch[n];
        if (b != curb) {
            atomicAdd(&pool[(size_t)curb * DH + t], acc);
            if (t == 0) atomicAdd(&gcnt[curb], cn);
            acc = 0.f; cn = 0; curb = b;
        }
        acc += x[(size_t)n * DH + t];
        ++cn;
    }
    atomicAdd(&pool[(size_t)curb * DH + t], acc);
    if (t == 0) atomicAdd(&gcnt[curb], cn);
}

__global__ void div_kernel(const float* __restrict__ pool, const int* __restrict__ gcnt,
                           float* __restrict__ out)
{
    int i = blockIdx.x * blockDim.x + threadIdx.x;
    if (i < NB * DH) {
        float c = (float)gcnt[i >> 7];
        out[i] = pool[i] / fmaxf(c, 1.0f);
    }
}

// ---------------- launch ----------------
extern "C" void kernel_launch(void* const* d_in, const int* in_sizes, int n_in,
                              void* d_out, int out_size, void* d_ws, size_t ws_size,
                              hipStream_t stream)
{
    const float* nf    = (const float*)d_in[0];
    const int*   esrc  = (const int*)d_in[1];
    const int*   edst  = esrc + N_EDGES;
    const float* ew    = (const float*)d_in[2];
    const int*   batch = (const int*)d_in[3];
    const float* Wp    = (const float*)d_in[4];
    const float* bp    = (const float*)d_in[5];
    const float* Wl[2]  = {(const float*)d_in[6],  (const float*)d_in[14]};
    const float* asl[2] = {(const float*)d_in[7],  (const float*)d_in[15]};
    const float* adl[2] = {(const float*)d_in[8],  (const float*)d_in[16]};
    const float* Wel[2] = {(const float*)d_in[9],  (const float*)d_in[17]};
    const float* ael[2] = {(const float*)d_in[10], (const float*)d_in[18]};
    const float* bl[2]  = {(const float*)d_in[11], (const float*)d_in[19]};
    const float* gl[2]  = {(const float*)d_in[12], (const float*)d_in[20]};
    const float* bel[2] = {(const float*)d_in[13], (const float*)d_in[21]};
    float* outp = (float*)d_out;

    char* w = (char*)d_ws;
    auto alloc = [&](size_t bytes) { char* p = w; w += (bytes + 255) & ~255ull; return p; };
    float* xA     = (float*)alloc((size_t)N_NODES * DH * 4);
    float* xB     = (float*)alloc((size_t)N_NODES * DH * 4);
    unsigned short* hbuf = (unsigned short*)alloc((size_t)N_NODES * DH * 2);
    float* asrc   = (float*)alloc((size_t)N_NODES * 4 * 4);
    float* adst   = (float*)alloc((size_t)N_NODES * 4 * 4);
    // contiguous zero-init group: pool | gcnt | ews | cnt  (one memset)
    float* pool   = (float*)alloc((size_t)NB * DH * 4);     // 32768 B
    int* gcnt     = (int*)alloc(256);
    float* ews    = (float*)alloc(256);
    int* cnt      = (int*)alloc((size_t)N_NODES * 4);
    int* scanned  = (int*)alloc((size_t)N_NODES * 4);
    int* bsums    = (int*)alloc(1024);
    int* ptr      = (int*)alloc((size_t)(N_NODES + 8) * 4);
    int* rank     = (int*)alloc((size_t)N_EDGES * 4);
    int2* recE    = (int2*)alloc((size_t)N_EDGES * 8);
    float* consts = (float*)alloc(256);

    hipMemsetAsync(pool, 0, (size_t)NB * DH * 4 + 256 + 256 + (size_t)N_NODES * 4, stream);

    const int sb = (N_NODES + 255) / 256;  // 196

    histew_kernel<<<1024, 256, 0, stream>>>(edst, ew, cnt, rank, ews);
    scan_a<<<sb, 256, 0, stream>>>(cnt, scanned, bsums);
    scan_b<<<1, 256, 0, stream>>>(bsums, sb, Wel[0], ael[0], Wel[1], ael[1], ews, consts);
    scan_c<<<sb, 256, 0, stream>>>(scanned, bsums, cnt, ptr);
    fill_kernel<<<(N_EDGES / 4 + 255) / 256, 256, 0, stream>>>(esrc, edst, ew, rank, ptr, recE);

    const int gb = (N_NODES + 63) / 64;  // 782
    mfma_gemm<DIN, false><<<gb, 256, 0, stream>>>(nf, Wp, bp, xA, N_NODES,
                                                  nullptr, nullptr, nullptr, nullptr);

    const float* xin = xA;
    float* xout = xB;
    for (int l = 0; l < 2; ++l) {
        mfma_gemm<DH, true><<<gb, 256, 0, stream>>>(xin, Wl[l], nullptr, hbuf, N_NODES,
                                                    asl[l], adl[l], asrc, adst);
        msg_kernel<<<N_NODES / MSG_NPB, 256, 0, stream>>>(
            hbuf, asrc, adst, xin, ptr, recE, consts, l,
            bl[l], gl[l], bel[l], xout);
        float* tmp = (float*)xin; xin = xout; xout = tmp;
    }

    pool_kernel<<<(N_NODES + PNODES - 1) / PNODES, 128, 0, stream>>>(xin, batch, pool, gcnt);
    div_kernel<<<(NB * DH + 255) / 256, 256, 0, stream>>>(pool, gcnt, outp);
}

// Round 3
// 374.091 us; speedup vs baseline: 1.1225x; 1.0116x over previous
//
#include <hip/hip_runtime.h>

#define N_NODES 50000
#define N_EDGES 800000
#define DIN 384
#define DH 128
#define NB 64
#define NEG 0.2f

// ---------------- bf16 helpers (exact bit ops) ----------------
__device__ __forceinline__ float bf2f(unsigned short u) {
    return __uint_as_float((unsigned)u << 16);
}
__device__ __forceinline__ unsigned short f2bf(float x) {  // RNE
    unsigned u = __float_as_uint(x);
    return (unsigned short)((u + 0x7fff + ((u >> 16) & 1)) >> 16);
}
__device__ __forceinline__ float sel4(float4 v, int k) {
    float r = v.x;
    r = (k == 1) ? v.y : r;
    r = (k == 2) ? v.z : r;
    r = (k == 3) ? v.w : r;
    return r;
}
using us8 = __attribute__((ext_vector_type(8))) unsigned short;
using short8 = __attribute__((ext_vector_type(8))) short;
using f32x4  = __attribute__((ext_vector_type(4))) float;

// ---------------- weight prep: transpose + bf16 convert (once) --------------
// Wt layouts: Wtp[128][384], Wt0[128][128], Wt1[128][128]  (n-major, bf16)
__global__ __launch_bounds__(256) void prep_w(const float* __restrict__ Wp,
        const float* __restrict__ W0, const float* __restrict__ W1,
        unsigned short* __restrict__ Wtp, unsigned short* __restrict__ Wt0,
        unsigned short* __restrict__ Wt1)
{
    const int i = blockIdx.x * 256 + threadIdx.x;
    if (i < DIN * DH) {
        const int k = i >> 7, n = i & 127;
        Wtp[(size_t)n * DIN + k] = f2bf(Wp[i]);
    }
    if (i < DH * DH) {
        const int k = i >> 7, n = i & 127;
        Wt0[(size_t)n * DH + k] = f2bf(W0[i]);
        Wt1[(size_t)n * DH + k] = f2bf(W1[i]);
    }
}

// ---------------- fused histogram + rank capture + edge-weight sum ----------
__global__ __launch_bounds__(256) void histew_kernel(const int* __restrict__ dst,
                                                     const float* __restrict__ ew,
                                                     int* __restrict__ cnt,
                                                     int* __restrict__ rank,
                                                     float* __restrict__ ews) {
    __shared__ float sred[4];
    const int tid = threadIdx.x;
    float v = 0.0f;
    for (int i = blockIdx.x * 256 + tid; i < N_EDGES; i += gridDim.x * 256) {
        rank[i] = atomicAdd(&cnt[dst[i]], 1);
        v += ew[i];
    }
    #pragma unroll
    for (int o = 32; o; o >>= 1) v += __shfl_down(v, o, 64);
    if ((tid & 63) == 0) sred[tid >> 6] = v;
    __syncthreads();
    if (tid == 0) atomicAdd(ews, sred[0] + sred[1] + sred[2] + sred[3]);
}

// ---------------- 3-dispatch parallel exclusive scan ----------------
__global__ void scan_a(const int* __restrict__ cnt, int* __restrict__ scanned,
                       int* __restrict__ bsums) {
    __shared__ int s[256];
    int tid = threadIdx.x;
    int i = blockIdx.x * 256 + tid;
    int v = (i < N_NODES) ? cnt[i] : 0;
    s[tid] = v; __syncthreads();
    for (int o = 1; o < 256; o <<= 1) {
        int t = (tid >= o) ? s[tid - o] : 0;
        __syncthreads();
        s[tid] += t;
        __syncthreads();
    }
    if (i < N_NODES) scanned[i] = s[tid] - v;  // exclusive
    if (tid == 255) bsums[blockIdx.x] = s[255];
}

// scan of block sums + one-time per-layer attention constants:
// consts[0..3] = cc layer0, consts[4..7] = cc layer1, consts[8] = mean(ew)
__global__ void scan_b(int* __restrict__ bsums, int nb,
                       const float* __restrict__ We0, const float* __restrict__ ae0,
                       const float* __restrict__ We1, const float* __restrict__ ae1,
                       const float* __restrict__ ews, float* __restrict__ consts) {
    __shared__ int s[256];
    int tid = threadIdx.x;
    int v = (tid < nb) ? bsums[tid] : 0;
    s[tid] = v; __syncthreads();
    for (int o = 1; o < 256; o <<= 1) {
        int t = (tid >= o) ? s[tid - o] : 0;
        __syncthreads();
        s[tid] += t;
        __syncthreads();
    }
    if (tid < nb) bsums[tid] = s[tid] - v;  // exclusive

    if (tid < 64) {
        const int l = tid;
        float p00 = We0[l] * ae0[l];
        float p01 = We0[l + 64] * ae0[l + 64];
        float p10 = We1[l] * ae1[l];
        float p11 = We1[l + 64] * ae1[l + 64];
        #pragma unroll
        for (int o = 1; o < 32; o <<= 1) {
            p00 += __shfl_xor(p00, o, 64); p01 += __shfl_xor(p01, o, 64);
            p10 += __shfl_xor(p10, o, 64); p11 += __shfl_xor(p11, o, 64);
        }
        const float c0 = __shfl(p00, 0, 64), c1 = __shfl(p00, 32, 64);
        const float c2 = __shfl(p01, 0, 64), c3 = __shfl(p01, 32, 64);
        const float d0 = __shfl(p10, 0, 64), d1 = __shfl(p10, 32, 64);
        const float d2 = __shfl(p11, 0, 64), d3 = __shfl(p11, 32, 64);
        if (l == 0) {
            consts[0] = c0; consts[1] = c1; consts[2] = c2; consts[3] = c3;
            consts[4] = d0; consts[5] = d1; consts[6] = d2; consts[7] = d3;
            consts[8] = ews[0] * (1.0f / N_EDGES);
        }
    }
}

__global__ void scan_c(const int* __restrict__ scanned, const int* __restrict__ bsums,
                       const int* __restrict__ cnt, int* __restrict__ ptr) {
    int i = blockIdx.x * 256 + threadIdx.x;
    if (i < N_NODES) {
        int p = scanned[i] + bsums[blockIdx.x];
        ptr[i] = p;
        if (i == N_NODES - 1) ptr[N_NODES] = p + cnt[i];
    }
}

// fill: atomic-free. 8 B records {src, ew_bits}; dst is implied by the CSR segment.
__global__ __launch_bounds__(256) void fill_kernel(const int* __restrict__ src,
                            const int* __restrict__ dst,
                            const float* __restrict__ ew,
                            const int* __restrict__ rank,
                            const int* __restrict__ ptr,
                            int2* __restrict__ recE) {
    const int e0 = (blockIdx.x * 256 + threadIdx.x) * 4;
    if (e0 >= N_EDGES) return;
    const int4 d4 = *(const int4*)(dst + e0);
    const int4 s4 = *(const int4*)(src + e0);
    const int4 r4 = *(const int4*)(rank + e0);
    const float4 w4 = *(const float4*)(ew + e0);
    recE[ptr[d4.x] + r4.x] = make_int2(s4.x, __float_as_int(w4.x));
    recE[ptr[d4.y] + r4.y] = make_int2(s4.y, __float_as_int(w4.y));
    recE[ptr[d4.z] + r4.z] = make_int2(s4.z, __float_as_int(w4.z));
    recE[ptr[d4.w] + r4.w] = make_int2(s4.w, __float_as_int(w4.w));
}

// ---------------- projection GEMM: [M,384]f32 @ Wt[128][384]bf16 -> f32 + bf16 ----
// BM=128 tile, 4 waves, acc[2][8] per wave (16 MFMA / K-step / wave).
__global__ __launch_bounds__(256) void mfma_gemm_proj(
    const float* __restrict__ A, const unsigned short* __restrict__ Wt,
    const float* __restrict__ bias, float* __restrict__ C,
    unsigned short* __restrict__ Cb, int M)
{
    constexpr int K = DIN, BM = 128, BK = 32, LS = 40;
    __shared__ unsigned short As[BM * LS];
    __shared__ unsigned short Bs[DH * LS];

    const int tid = threadIdx.x;
    const int w = tid >> 6, l = tid & 63;
    const int lane16 = l & 15, quad = l >> 4;
    const int m0 = blockIdx.x * BM;

    f32x4 acc[2][8] = {};

    const int ar = tid >> 1, ah = tid & 1;   // 128 rows x 2 half-tiles of 16 floats
    int arow = m0 + ar; if (arow >= M) arow = M - 1;
    const float* Ap = A + (size_t)arow * K;

    for (int k0 = 0; k0 < K; k0 += BK) {
        __syncthreads();
        #pragma unroll
        for (int j = 0; j < 4; ++j) {
            float4 v = *(const float4*)(Ap + k0 + ah * 16 + j * 4);
            ushort4 u = {f2bf(v.x), f2bf(v.y), f2bf(v.z), f2bf(v.w)};
            *(ushort4*)&As[ar * LS + ah * 16 + j * 4] = u;
        }
        #pragma unroll
        for (int i = 0; i < 2; ++i) {
            const int idx = tid + 256 * i;
            const int bn = idx >> 2, seg = idx & 3;
            us8 v = *(const us8*)(Wt + (size_t)bn * K + k0 + seg * 8);
            *(us8*)&Bs[bn * LS + seg * 8] = v;
        }
        __syncthreads();
        short8 af0 = *(short8*)&As[(w * 32 + lane16) * LS + quad * 8];
        short8 af1 = *(short8*)&As[(w * 32 + 16 + lane16) * LS + quad * 8];
        #pragma unroll
        for (int nt = 0; nt < 8; ++nt) {
            short8 bf = *(short8*)&Bs[(nt * 16 + lane16) * LS + quad * 8];
            acc[0][nt] = __builtin_amdgcn_mfma_f32_16x16x32_bf16(af0, bf, acc[0][nt], 0, 0, 0);
            acc[1][nt] = __builtin_amdgcn_mfma_f32_16x16x32_bf16(af1, bf, acc[1][nt], 0, 0, 0);
        }
    }

    #pragma unroll
    for (int r2 = 0; r2 < 2; ++r2) {
        const int orow0 = m0 + w * 32 + r2 * 16 + quad * 4;
        #pragma unroll
        for (int nt = 0; nt < 8; ++nt) {
            const int col = nt * 16 + lane16;
            const float bv = bias[col];
            #pragma unroll
            for (int r = 0; r < 4; ++r) {
                const int row = orow0 + r;
                if (row < M) {
                    const float v = acc[r2][nt][r] + bv;
                    C[(size_t)row * DH + col] = v;
                    Cb[(size_t)row * DH + col] = f2bf(v);
                }
            }
        }
    }
}

// ---------------- layer GEMM: [M,128]bf16 @ Wt[128][128]bf16 -> h bf16 + logits ----
__global__ __launch_bounds__(256) void mfma_gemm_layer(
    const unsigned short* __restrict__ Ab, const unsigned short* __restrict__ Wt,
    unsigned short* __restrict__ Hout, int M,
    const float* __restrict__ a_s, const float* __restrict__ a_d,
    float* __restrict__ asrc_o, float* __restrict__ adst_o)
{
    constexpr int K = DH, BM = 64, BK = 32, LS = 40;
    __shared__ unsigned short As[BM * LS];
    __shared__ unsigned short Bs[DH * LS];

    const int tid = threadIdx.x;
    const int w = tid >> 6, l = tid & 63;
    const int lane16 = l & 15, quad = l >> 4;
    const int m0 = blockIdx.x * BM;

    f32x4 acc[8] = {};

    const int ar = tid >> 2, aseg = tid & 3;  // 64 rows x 4 segments of 8 bf16
    int arow = m0 + ar; if (arow >= M) arow = M - 1;
    const unsigned short* Ap = Ab + (size_t)arow * K;

    for (int k0 = 0; k0 < K; k0 += BK) {
        __syncthreads();
        {
            us8 v = *(const us8*)(Ap + k0 + aseg * 8);
            *(us8*)&As[ar * LS + aseg * 8] = v;
        }
        #pragma unroll
        for (int i = 0; i < 2; ++i) {
            const int idx = tid + 256 * i;
            const int bn = idx >> 2, seg = idx & 3;
            us8 v = *(const us8*)(Wt + (size_t)bn * K + k0 + seg * 8);
            *(us8*)&Bs[bn * LS + seg * 8] = v;
        }
        __syncthreads();
        short8 af = *(short8*)&As[(w * 16 + lane16) * LS + quad * 8];
        #pragma unroll
        for (int nt = 0; nt < 8; ++nt) {
            short8 bf = *(short8*)&Bs[(nt * 16 + lane16) * LS + quad * 8];
            acc[nt] = __builtin_amdgcn_mfma_f32_16x16x32_bf16(af, bf, acc[nt], 0, 0, 0);
        }
    }

    const int orow0 = m0 + w * 16 + quad * 4;
    #pragma unroll
    for (int nt = 0; nt < 8; ++nt) {
        const int col = nt * 16 + lane16;
        #pragma unroll
        for (int r = 0; r < 4; ++r) {
            const int row = orow0 + r;
            if (row < M)
                Hout[(size_t)row * DH + col] = f2bf(acc[nt][r]);
        }
    }

    // attention logits: asrc[row][hd] = sum_{f in head} h[row][hd*32+f]*a_s[hd][f]
    float psh[4][4] = {}, pdh[4][4] = {};   // [head][r]
    #pragma unroll
    for (int nt = 0; nt < 8; ++nt) {
        const int hd = nt >> 1;
        const float asv = a_s[nt * 16 + lane16];
        const float adv = a_d[nt * 16 + lane16];
        #pragma unroll
        for (int r = 0; r < 4; ++r) {
            psh[hd][r] = fmaf(acc[nt][r], asv, psh[hd][r]);
            pdh[hd][r] = fmaf(acc[nt][r], adv, pdh[hd][r]);
        }
    }
    #pragma unroll
    for (int o = 1; o < 16; o <<= 1) {
        #pragma unroll
        for (int hd = 0; hd < 4; ++hd)
            #pragma unroll
            for (int r = 0; r < 4; ++r) {
                psh[hd][r] += __shfl_xor(psh[hd][r], o, 64);
                pdh[hd][r] += __shfl_xor(pdh[hd][r], o, 64);
            }
    }
    if (lane16 == 0) {
        #pragma unroll
        for (int r = 0; r < 4; ++r) {
            const int row = orow0 + r;
            if (row < M) {
                float4 o1 = {psh[0][r], psh[1][r], psh[2][r], psh[3][r]};
                float4 o2 = {pdh[0][r], pdh[1][r], pdh[2][r], pdh[3][r]};
                *(float4*)(asrc_o + (size_t)row * 4) = o1;
                *(float4*)(adst_o + (size_t)row * 4) = o2;
            }
        }
    }
}

// ---------------- msg: fused alpha + gather + softmax-norm + LN + ELU + res ----
// One node per 16-lane group (4 nodes/wave, 16 nodes/block). Each lane owns 8
// channels (c8*8..c8*8+7). No cross-parity reduces; only LN's 16-lane reduce.
#define MSG_NPB 16
__global__ __launch_bounds__(256) void msg_kernel(
    const unsigned short* __restrict__ h, const float* __restrict__ asrc,
    const float* __restrict__ adst, const float* __restrict__ xres,
    const int* __restrict__ indptr, const int2* __restrict__ recE,
    const float* __restrict__ consts, const int layer,
    const float* __restrict__ bias, const float* __restrict__ gamma,
    const float* __restrict__ beta, float* __restrict__ xout,
    unsigned short* __restrict__ xob)
{
    const int l = threadIdx.x & 63;
    const int wv = threadIdx.x >> 6;
    const int grp = l >> 4;          // node slot within wave (0..3)
    const int c8 = l & 15;           // channel lane: channels [c8*8, c8*8+8)
    const int hd8 = c8 >> 2;         // head of those channels

    const int n = blockIdx.x * MSG_NPB + wv * 4 + grp;   // grid is exact: 3125*16=50000

    const float4 ccv = *(const float4*)(consts + layer * 4);
    const float cc_l = sel4(ccv, hd8);
    const float ewm = consts[8];
    const unsigned short* hb = h + c8 * 8;

    const int st = indptr[n];
    const int deg = indptr[n + 1] - st;
    const float ad_l = adst[(size_t)n * 4 + hd8];
    const float as_l = asrc[(size_t)n * 4 + hd8];

    // self-loop coefficient (|alpha| << 1 -> exp without max-shift is exact softmax)
    float a0 = as_l + ad_l + ewm * cc_l;
    a0 = a0 > 0.f ? a0 : NEG * a0;
    const float pv0_l = __expf(a0);

    float dsum = 0.f;
    float acc8[8];
    {
        us8 u = *(const us8*)(hb + (size_t)n * DH);
        #pragma unroll
        for (int i = 0; i < 8; ++i) acc8[i] = pv0_l * bf2f(u[i]);
    }

    const int2* rq = recE + st;
    int e = 0;
    for (; e + 3 < deg; e += 4) {
        const int2 r0 = rq[e],     r1 = rq[e + 1];
        const int2 r2 = rq[e + 2], r3 = rq[e + 3];
        const float av0 = asrc[(size_t)r0.x * 4 + hd8];
        const float av1 = asrc[(size_t)r1.x * 4 + hd8];
        const float av2 = asrc[(size_t)r2.x * 4 + hd8];
        const float av3 = asrc[(size_t)r3.x * 4 + hd8];
        us8 u0 = *(const us8*)(hb + (size_t)r0.x * DH);
        us8 u1 = *(const us8*)(hb + (size_t)r1.x * DH);
        us8 u2 = *(const us8*)(hb + (size_t)r2.x * DH);
        us8 u3 = *(const us8*)(hb + (size_t)r3.x * DH);
        float al0 = av0 + ad_l + __int_as_float(r0.y) * cc_l;
        float al1 = av1 + ad_l + __int_as_float(r1.y) * cc_l;
        float al2 = av2 + ad_l + __int_as_float(r2.y) * cc_l;
        float al3 = av3 + ad_l + __int_as_float(r3.y) * cc_l;
        al0 = al0 > 0.f ? al0 : NEG * al0;
        al1 = al1 > 0.f ? al1 : NEG * al1;
        al2 = al2 > 0.f ? al2 : NEG * al2;
        al3 = al3 > 0.f ? al3 : NEG * al3;
        const float c0 = __expf(al0), c1 = __expf(al1);
        const float c2 = __expf(al2), c3 = __expf(al3);
        dsum += (c0 + c1) + (c2 + c3);
        #pragma unroll
        for (int i = 0; i < 8; ++i)
            acc8[i] = fmaf(c0, bf2f(u0[i]),
                      fmaf(c1, bf2f(u1[i]),
                      fmaf(c2, bf2f(u2[i]),
                      fmaf(c3, bf2f(u3[i]), acc8[i]))));
    }
    for (; e < deg; ++e) {
        const int2 r = rq[e];
        const float av = asrc[(size_t)r.x * 4 + hd8];
        us8 u = *(const us8*)(hb + (size_t)r.x * DH);
        float al = av + ad_l + __int_as_float(r.y) * cc_l;
        al = al > 0.f ? al : NEG * al;
        const float c = __expf(al);
        dsum += c;
        #pragma unroll
        for (int i = 0; i < 8; ++i) acc8[i] = fmaf(c, bf2f(u[i]), acc8[i]);
    }

    const float inv_d = 1.0f / (dsum + pv0_l + 1e-16f);
    const float4 b4a = *(const float4*)(bias + c8 * 8);
    const float4 b4b = *(const float4*)(bias + c8 * 8 + 4);
    float y[8];
    y[0] = acc8[0] * inv_d + b4a.x; y[1] = acc8[1] * inv_d + b4a.y;
    y[2] = acc8[2] * inv_d + b4a.z; y[3] = acc8[3] * inv_d + b4a.w;
    y[4] = acc8[4] * inv_d + b4b.x; y[5] = acc8[5] * inv_d + b4b.y;
    y[6] = acc8[6] * inv_d + b4b.z; y[7] = acc8[7] * inv_d + b4b.w;

    float s1 = 0.f, s2 = 0.f;
    #pragma unroll
    for (int i = 0; i < 8; ++i) { s1 += y[i]; s2 += y[i] * y[i]; }
    #pragma unroll
    for (int o = 1; o < 16; o <<= 1) {   // stays within the 16-lane group
        s1 += __shfl_xor(s1, o, 64);
        s2 += __shfl_xor(s2, o, 64);
    }
    const float mu = s1 * (1.0f / DH);
    const float var = s2 * (1.0f / DH) - mu * mu;
    const float rs = rsqrtf(var + 1e-5f);

    const float4 g4a = *(const float4*)(gamma + c8 * 8);
    const float4 g4b = *(const float4*)(gamma + c8 * 8 + 4);
    const float4 e4a = *(const float4*)(beta + c8 * 8);
    const float4 e4b = *(const float4*)(beta + c8 * 8 + 4);
    const float4 r4a = *(const float4*)(xres + (size_t)n * DH + c8 * 8);
    const float4 r4b = *(const float4*)(xres + (size_t)n * DH + c8 * 8 + 4);
    const float gv[8] = {g4a.x, g4a.y, g4a.z, g4a.w, g4b.x, g4b.y, g4b.z, g4b.w};
    const float ev[8] = {e4a.x, e4a.y, e4a.z, e4a.w, e4b.x, e4b.y, e4b.z, e4b.w};
    const float rv[8] = {r4a.x, r4a.y, r4a.z, r4a.w, r4b.x, r4b.y, r4b.z, r4b.w};
    float z[8];
    #pragma unroll
    for (int i = 0; i < 8; ++i) {
        float t = (y[i] - mu) * rs * gv[i] + ev[i];
        z[i] = (t > 0.f ? t : __expf(t) - 1.0f) + rv[i];
    }
    *(float4*)(xout + (size_t)n * DH + c8 * 8)     = *(float4*)&z[0];
    *(float4*)(xout + (size_t)n * DH + c8 * 8 + 4) = *(float4*)&z[4];
    if (xob) {
        ushort4 ub0 = {f2bf(z[0]), f2bf(z[1]), f2bf(z[2]), f2bf(z[3])};
        ushort4 ub1 = {f2bf(z[4]), f2bf(z[5]), f2bf(z[6]), f2bf(z[7])};
        *(ushort4*)(xob + (size_t)n * DH + c8 * 8)     = ub0;
        *(ushort4*)(xob + (size_t)n * DH + c8 * 8 + 4) = ub1;
    }
}

// ---------------- global mean pool ----------------
#define PNODES 64
__global__ __launch_bounds__(128) void pool_kernel(const float* __restrict__ x,
        const int* __restrict__ batch, float* __restrict__ pool, int* __restrict__ gcnt)
{
    int t = threadIdx.x;
    int n0 = blockIdx.x * PNODES;
    if (n0 >= N_NODES) return;
    int n1 = min(n0 + PNODES, N_NODES);
    float acc = 0.f; int cn = 0;
    int curb = batch[n0];
    for (int n = n0; n < n1; ++n) {
        int b = batch[n];
        if (b != curb) {
            atomicAdd(&pool[(size_t)curb * DH + t], acc);
            if (t == 0) atomicAdd(&gcnt[curb], cn);
            acc = 0.f; cn = 0; curb = b;
        }
        acc += x[(size_t)n * DH + t];
        ++cn;
    }
    atomicAdd(&pool[(size_t)curb * DH + t], acc);
    if (t == 0) atomicAdd(&gcnt[curb], cn);
}

__global__ void div_kernel(const float* __restrict__ pool, const int* __restrict__ gcnt,
                           float* __restrict__ out)
{
    int i = blockIdx.x * blockDim.x + threadIdx.x;
    if (i < NB * DH) {
        float c = (float)gcnt[i >> 7];
        out[i] = pool[i] / fmaxf(c, 1.0f);
    }
}

// ---------------- launch ----------------
extern "C" void kernel_launch(void* const* d_in, const int* in_sizes, int n_in,
                              void* d_out, int out_size, void* d_ws, size_t ws_size,
                              hipStream_t stream)
{
    const float* nf    = (const float*)d_in[0];
    const int*   esrc  = (const int*)d_in[1];
    const int*   edst  = esrc + N_EDGES;
    const float* ew    = (const float*)d_in[2];
    const int*   batch = (const int*)d_in[3];
    const float* Wp    = (const float*)d_in[4];
    const float* bp    = (const float*)d_in[5];
    const float* Wl[2]  = {(const float*)d_in[6],  (const float*)d_in[14]};
    const float* asl[2] = {(const float*)d_in[7],  (const float*)d_in[15]};
    const float* adl[2] = {(const float*)d_in[8],  (const float*)d_in[16]};
    const float* Wel[2] = {(const float*)d_in[9],  (const float*)d_in[17]};
    const float* ael[2] = {(const float*)d_in[10], (const float*)d_in[18]};
    const float* bl[2]  = {(const float*)d_in[11], (const float*)d_in[19]};
    const float* gl[2]  = {(const float*)d_in[12], (const float*)d_in[20]};
    const float* bel[2] = {(const float*)d_in[13], (const float*)d_in[21]};
    float* outp = (float*)d_out;

    char* w = (char*)d_ws;
    auto alloc = [&](size_t bytes) { char* p = w; w += (bytes + 255) & ~255ull; return p; };
    float* xA     = (float*)alloc((size_t)N_NODES * DH * 4);
    float* xB     = (float*)alloc((size_t)N_NODES * DH * 4);
    unsigned short* hbuf = (unsigned short*)alloc((size_t)N_NODES * DH * 2);
    unsigned short* xb   = (unsigned short*)alloc((size_t)N_NODES * DH * 2);  // bf16 A for layer GEMMs
    float* asrc   = (float*)alloc((size_t)N_NODES * 4 * 4);
    float* adst   = (float*)alloc((size_t)N_NODES * 4 * 4);
    // contiguous zero-init group: pool | gcnt | ews | cnt  (one memset)
    float* pool   = (float*)alloc((size_t)NB * DH * 4);     // 32768 B
    int* gcnt     = (int*)alloc(256);
    float* ews    = (float*)alloc(256);
    int* cnt      = (int*)alloc((size_t)N_NODES * 4);
    int* scanned  = (int*)alloc((size_t)N_NODES * 4);
    int* bsums    = (int*)alloc(1024);
    int* ptr      = (int*)alloc((size_t)(N_NODES + 8) * 4);
    int* rank     = (int*)alloc((size_t)N_EDGES * 4);
    int2* recE    = (int2*)alloc((size_t)N_EDGES * 8);
    float* consts = (float*)alloc(256);
    unsigned short* Wtp = (unsigned short*)alloc((size_t)DH * DIN * 2);
    unsigned short* Wt0 = (unsigned short*)alloc((size_t)DH * DH * 2);
    unsigned short* Wt1 = (unsigned short*)alloc((size_t)DH * DH * 2);
    unsigned short* Wts[2] = {Wt0, Wt1};

    hipMemsetAsync(pool, 0, (size_t)NB * DH * 4 + 256 + 256 + (size_t)N_NODES * 4, stream);

    const int sb = (N_NODES + 255) / 256;  // 196

    prep_w<<<(DIN * DH + 255) / 256, 256, 0, stream>>>(Wp, Wl[0], Wl[1], Wtp, Wt0, Wt1);
    histew_kernel<<<1024, 256, 0, stream>>>(edst, ew, cnt, rank, ews);
    scan_a<<<sb, 256, 0, stream>>>(cnt, scanned, bsums);
    scan_b<<<1, 256, 0, stream>>>(bsums, sb, Wel[0], ael[0], Wel[1], ael[1], ews, consts);
    scan_c<<<sb, 256, 0, stream>>>(scanned, bsums, cnt, ptr);
    fill_kernel<<<(N_EDGES / 4 + 255) / 256, 256, 0, stream>>>(esrc, edst, ew, rank, ptr, recE);

    mfma_gemm_proj<<<(N_NODES + 127) / 128, 256, 0, stream>>>(nf, Wtp, bp, xA, xb, N_NODES);

    const int gb = (N_NODES + 63) / 64;  // 782
    const float* xin = xA;
    float* xout = xB;
    for (int l = 0; l < 2; ++l) {
        mfma_gemm_layer<<<gb, 256, 0, stream>>>(xb, Wts[l], hbuf, N_NODES,
                                                asl[l], adl[l], asrc, adst);
        msg_kernel<<<N_NODES / MSG_NPB, 256, 0, stream>>>(
            hbuf, asrc, adst, xin, ptr, recE, consts, l,
            bl[l], gl[l], bel[l], xout, (l == 0) ? xb : nullptr);
        float* tmp = (float*)xin; xin = xout; xout = tmp;
    }

    pool_kernel<<<(N_NODES + PNODES - 1) / PNODES, 128, 0, stream>>>(xin, batch, pool, gcnt);
    div_kernel<<<(NB * DH + 255) / 256, 256, 0, stream>>>(pool, gcnt, outp);
}